// Round 2
// baseline (94.555 us; speedup 1.0000x reference)
//
#include <hip/hip_runtime.h>

// Depthwise ConvTranspose2d: x(16,64,64,256) f32 -> y(16,128,128,256) f32
// k=4, stride=2, pad=1, NHWC.
// Output 2x2 block {2i-1,2i}x{2j-1,2j} depends on input block {i-1,i}x{j-1,j}.
// V2: one wave = 13-block horizontal strip at fixed (n,i); register-carried
// column reuse (2 loads/iter instead of 4) + bijective XCD-chunked task remap
// so vertical stencil overlap hits the owning XCD's L2.

#define Hh 64
#define Ww 64
#define C4 64          // 256 channels / 4 per float4; one pixel = 64 lanes * float4
#define OWs 128
#define TSTRIP 13      // 65 = 5 * 13 block-columns per row
#define NTASK_PER_N 325  // 65 rows * 5 strips
#define NBLK 1300      // 5200 tasks / 4 waves per block

__device__ __forceinline__ void fma4(float4& a, const float4& x, const float4& w) {
    a.x = fmaf(x.x, w.x, a.x);
    a.y = fmaf(x.y, w.y, a.y);
    a.z = fmaf(x.z, w.z, a.z);
    a.w = fmaf(x.w, w.w, a.w);
}

__global__ __launch_bounds__(256, 4) void dwct_kernel(
    const float* __restrict__ xp_, const float* __restrict__ wp,
    const float* __restrict__ bp, float* __restrict__ op)
{
    const int lane  = threadIdx.x & 63;
    const int wslot = threadIdx.x >> 6;

    // Bijective XCD-chunk remap (m204 form): blocks with the same blockIdx%8
    // (same XCD under round-robin dispatch) own a contiguous task chunk.
    const int q = NBLK / 8, r = NBLK % 8;          // 162, 4
    const int xcd = blockIdx.x % 8, ord = blockIdx.x / 8;
    const int newb = (xcd < r ? xcd * (q + 1) : r * (q + 1) + (xcd - r) * q) + ord;
    const int task = newb * 4 + wslot;             // 0..5199

    const int n   = task / NTASK_PER_N;
    const int rem = task - n * NTASK_PER_N;
    const int i   = rem / 5;                       // block-row 0..64
    const int s   = rem - i * 5;                   // strip 0..4
    const int j0  = s * TSTRIP;

    const float4* x4 = reinterpret_cast<const float4*>(xp_);
    const float4* w4 = reinterpret_cast<const float4*>(wp);
    const float4* b4 = reinterpret_cast<const float4*>(bp);
    float4*       o4 = reinterpret_cast<float4*>(op);

    // Hoist the 4x4 depthwise kernel (this lane's 4 channels): wv[kh*4+kw]
    float4 wv[16];
#pragma unroll
    for (int t = 0; t < 16; ++t) wv[t] = w4[t * C4 + lane];
    const float4 bv = b4[lane];
    const float4 z  = make_float4(0.f, 0.f, 0.f, 0.f);

    const bool p0 = (i > 0), p1 = (i < Hh);        // input rows i-1 / i valid
    const int xb0 = n * (Hh * Ww * C4) + (i - 1) * (Ww * C4) + lane;  // row i-1
    const int xb1 = xb0 + Ww * C4;                                    // row i
    const int ob  = n * (2 * Hh * OWs * C4);
    const int orow0 = ob + (2 * i - 1) * (OWs * C4) + lane;           // oh = 2i-1
    const int orow1 = orow0 + OWs * C4;                               // oh = 2i

    // Prime: previous column (j0-1) and current column (j0).
    float4 xp0 = z, xp1 = z, xc0 = z, xc1 = z;
    if (j0 > 0) {                                  // j0-1 in [0,64) when s>0
        if (p0) xp0 = x4[xb0 + (j0 - 1) * C4];
        if (p1) xp1 = x4[xb1 + (j0 - 1) * C4];
    }
    if (p0) xc0 = x4[xb0 + j0 * C4];               // j0 <= 52, always a valid col
    if (p1) xc1 = x4[xb1 + j0 * C4];

    for (int t = 0; t < TSTRIP; ++t) {
        const int j = j0 + t;

        // Prefetch next column (one iteration ahead).
        float4 xn0 = z, xn1 = z;
        if (j + 1 < Ww) {
            if (p0) xn0 = x4[xb0 + (j + 1) * C4];
            if (p1) xn1 = x4[xb1 + (j + 1) * C4];
        }

        // xp* = col j-1, xc* = col j.  Taps per round-0 verified mapping.
        float4 o00 = bv, o01 = bv, o10 = bv, o11 = bv;
        fma4(o00, xp0, wv[10]); fma4(o00, xc0, wv[8]);
        fma4(o00, xp1, wv[2]);  fma4(o00, xc1, wv[0]);

        fma4(o01, xp0, wv[11]); fma4(o01, xc0, wv[9]);
        fma4(o01, xp1, wv[3]);  fma4(o01, xc1, wv[1]);

        fma4(o10, xp0, wv[14]); fma4(o10, xc0, wv[12]);
        fma4(o10, xp1, wv[6]);  fma4(o10, xc1, wv[4]);

        fma4(o11, xp0, wv[15]); fma4(o11, xc0, wv[13]);
        fma4(o11, xp1, wv[7]);  fma4(o11, xc1, wv[5]);

        const int c0 = (2 * j - 1) * C4;           // ow = 2j-1
        if (p0) {
            if (j > 0)  o4[orow0 + c0]      = o00;
            if (j < Ww) o4[orow0 + c0 + C4] = o01;
        }
        if (p1) {
            if (j > 0)  o4[orow1 + c0]      = o10;
            if (j < Ww) o4[orow1 + c0 + C4] = o11;
        }

        xp0 = xc0; xp1 = xc1; xc0 = xn0; xc1 = xn1;
    }
}

extern "C" void kernel_launch(void* const* d_in, const int* in_sizes, int n_in,
                              void* d_out, int out_size, void* d_ws, size_t ws_size,
                              hipStream_t stream) {
    const float* x = (const float*)d_in[0];
    const float* w = (const float*)d_in[1];
    const float* b = (const float*)d_in[2];
    float* out = (float*)d_out;

    hipLaunchKernelGGL(dwct_kernel, dim3(NBLK), dim3(256), 0, stream, x, w, b, out);
}

// Round 4
// 60.630 us; speedup vs baseline: 1.5595x; 1.5595x over previous
//
#include <hip/hip_runtime.h>

// Depthwise ConvTranspose2d: x(16,64,64,256) f32 -> y(16,128,128,256) f32
// k=4, stride=2, pad=1, NHWC.
// V3b = V2 + non-temporal output stores, using clang ext_vector float4 so the
// nontemporal builtin accepts the pointer (HIP's float4 struct is rejected).

#define Hh 64
#define Ww 64
#define C4 64          // 256 channels / 4 per f4; one pixel = 64 lanes * f4
#define OWs 128
#define TSTRIP 13      // 65 = 5 * 13 block-columns per row
#define NTASK_PER_N 325  // 65 rows * 5 strips
#define NBLK 1300      // 5200 tasks / 4 waves per block

typedef float f4 __attribute__((ext_vector_type(4)));

__device__ __forceinline__ void fma4(f4& a, const f4& x, const f4& w) {
    a.x = fmaf(x.x, w.x, a.x);
    a.y = fmaf(x.y, w.y, a.y);
    a.z = fmaf(x.z, w.z, a.z);
    a.w = fmaf(x.w, w.w, a.w);
}

__global__ __launch_bounds__(256, 4) void dwct_kernel(
    const float* __restrict__ xp_, const float* __restrict__ wp,
    const float* __restrict__ bp, float* __restrict__ op)
{
    const int lane  = threadIdx.x & 63;
    const int wslot = threadIdx.x >> 6;

    // Bijective XCD-chunk remap (m204 form).
    const int q = NBLK / 8, r = NBLK % 8;          // 162, 4
    const int xcd = blockIdx.x % 8, ord = blockIdx.x / 8;
    const int newb = (xcd < r ? xcd * (q + 1) : r * (q + 1) + (xcd - r) * q) + ord;
    const int task = newb * 4 + wslot;             // 0..5199

    const int n   = task / NTASK_PER_N;
    const int rem = task - n * NTASK_PER_N;
    const int i   = rem / 5;                       // block-row 0..64
    const int s   = rem - i * 5;                   // strip 0..4
    const int j0  = s * TSTRIP;

    const f4* x4 = reinterpret_cast<const f4*>(xp_);
    const f4* w4 = reinterpret_cast<const f4*>(wp);
    const f4* b4 = reinterpret_cast<const f4*>(bp);
    f4*       o4 = reinterpret_cast<f4*>(op);

    // Hoist the 4x4 depthwise kernel (this lane's 4 channels): wv[kh*4+kw]
    f4 wv[16];
#pragma unroll
    for (int t = 0; t < 16; ++t) wv[t] = w4[t * C4 + lane];
    const f4 bv = b4[lane];
    const f4 z  = (f4){0.f, 0.f, 0.f, 0.f};

    const bool p0 = (i > 0), p1 = (i < Hh);        // input rows i-1 / i valid
    const int xb0 = n * (Hh * Ww * C4) + (i - 1) * (Ww * C4) + lane;  // row i-1
    const int xb1 = xb0 + Ww * C4;                                    // row i
    const int ob  = n * (2 * Hh * OWs * C4);
    const int orow0 = ob + (2 * i - 1) * (OWs * C4) + lane;           // oh = 2i-1
    const int orow1 = orow0 + OWs * C4;                               // oh = 2i

    // Prime: previous column (j0-1) and current column (j0).
    f4 xp0 = z, xp1 = z, xc0 = z, xc1 = z;
    if (j0 > 0) {
        if (p0) xp0 = x4[xb0 + (j0 - 1) * C4];
        if (p1) xp1 = x4[xb1 + (j0 - 1) * C4];
    }
    if (p0) xc0 = x4[xb0 + j0 * C4];
    if (p1) xc1 = x4[xb1 + j0 * C4];

    for (int t = 0; t < TSTRIP; ++t) {
        const int j = j0 + t;

        // Prefetch next column (one iteration ahead).
        f4 xn0 = z, xn1 = z;
        if (j + 1 < Ww) {
            if (p0) xn0 = x4[xb0 + (j + 1) * C4];
            if (p1) xn1 = x4[xb1 + (j + 1) * C4];
        }

        f4 o00 = bv, o01 = bv, o10 = bv, o11 = bv;
        fma4(o00, xp0, wv[10]); fma4(o00, xc0, wv[8]);
        fma4(o00, xp1, wv[2]);  fma4(o00, xc1, wv[0]);

        fma4(o01, xp0, wv[11]); fma4(o01, xc0, wv[9]);
        fma4(o01, xp1, wv[3]);  fma4(o01, xc1, wv[1]);

        fma4(o10, xp0, wv[14]); fma4(o10, xc0, wv[12]);
        fma4(o10, xp1, wv[6]);  fma4(o10, xc1, wv[4]);

        fma4(o11, xp0, wv[15]); fma4(o11, xc0, wv[13]);
        fma4(o11, xp1, wv[7]);  fma4(o11, xc1, wv[5]);

        const int c0 = (2 * j - 1) * C4;           // ow = 2j-1
        if (p0) {
            if (j > 0)  __builtin_nontemporal_store(o00, &o4[orow0 + c0]);
            if (j < Ww) __builtin_nontemporal_store(o01, &o4[orow0 + c0 + C4]);
        }
        if (p1) {
            if (j > 0)  __builtin_nontemporal_store(o10, &o4[orow1 + c0]);
            if (j < Ww) __builtin_nontemporal_store(o11, &o4[orow1 + c0 + C4]);
        }

        xp0 = xc0; xp1 = xc1; xc0 = xn0; xc1 = xn1;
    }
}

extern "C" void kernel_launch(void* const* d_in, const int* in_sizes, int n_in,
                              void* d_out, int out_size, void* d_ws, size_t ws_size,
                              hipStream_t stream) {
    const float* x = (const float*)d_in[0];
    const float* w = (const float*)d_in[1];
    const float* b = (const float*)d_in[2];
    float* out = (float*)d_out;

    hipLaunchKernelGGL(dwct_kernel, dim3(NBLK), dim3(256), 0, stream, x, w, b, out);
}

// Round 5
// 56.603 us; speedup vs baseline: 1.6705x; 1.0711x over previous
//
#include <hip/hip_runtime.h>

// Depthwise ConvTranspose2d: x(16,64,64,256) f32 -> y(16,128,128,256) f32
// k=4, stride=2, pad=1, NHWC.
// V4 = V3b + persistent balanced launch: exactly 1024 blocks (4/CU, all
// resident, no straggler batch). Each of 4096 waves owns a contiguous chunk
// of the 67600 block-column tasks (16-17 each), register-carrying the input
// columns within each row-run. nt stores retained (R4's +36% win).

#define Hh 64
#define Ww 64
#define C4 64            // 256 channels / 4 per f4; one pixel = 64 lanes * f4
#define OWs 128
#define NBLK 1024
#define TOTAL 67600      // 16 images * 65 * 65 block-columns
#define LOGW 12          // 4096 waves

typedef float f4 __attribute__((ext_vector_type(4)));

__device__ __forceinline__ void fma4(f4& a, const f4& x, const f4& w) {
    a.x = fmaf(x.x, w.x, a.x);
    a.y = fmaf(x.y, w.y, a.y);
    a.z = fmaf(x.z, w.z, a.z);
    a.w = fmaf(x.w, w.w, a.w);
}

__global__ __launch_bounds__(256, 4) void dwct_kernel(
    const float* __restrict__ xp_, const float* __restrict__ wp,
    const float* __restrict__ bp, float* __restrict__ op)
{
    const int lane  = threadIdx.x & 63;
    const int wslot = threadIdx.x >> 6;

    // Bijective XCD-chunk remap (NBLK % 8 == 0): same-XCD blocks get a
    // contiguous ~2-image span, keeping vertical stencil reuse XCD-local.
    const int xcd = blockIdx.x & 7, ord = blockIdx.x >> 3;
    const int newb = xcd * (NBLK / 8) + ord;
    const unsigned wr = (unsigned)(newb * 4 + wslot);          // 0..4095

    // This wave's contiguous task range [g, g1) of block-columns.
    int g        = (int)(((unsigned long long)wr * TOTAL) >> LOGW);
    const int g1 = (int)(((unsigned long long)(wr + 1) * TOTAL) >> LOGW);

    const f4* x4 = reinterpret_cast<const f4*>(xp_);
    const f4* w4 = reinterpret_cast<const f4*>(wp);
    const f4* b4 = reinterpret_cast<const f4*>(bp);
    f4*       o4 = reinterpret_cast<f4*>(op);

    // Hoist the 4x4 depthwise kernel (this lane's 4 channels): wv[kh*4+kw]
    f4 wv[16];
#pragma unroll
    for (int t = 0; t < 16; ++t) wv[t] = w4[t * C4 + lane];
    const f4 bv = b4[lane];
    const f4 z  = (f4){0.f, 0.f, 0.f, 0.f};

    while (g < g1) {
        int n   = g / 4225;                  // 65*65
        int rem = g - n * 4225;
        int i   = rem / 65;                  // block-row 0..64
        int j   = rem - i * 65;              // block-col 0..64
        int run = 65 - j;
        if (run > g1 - g) run = g1 - g;

        const bool p0 = (i > 0), p1 = (i < Hh);
        const int xb0 = n * (Hh * Ww * C4) + (i - 1) * (Ww * C4) + lane; // row i-1
        const int xb1 = xb0 + Ww * C4;                                   // row i
        const int orow0 = n * (2 * Hh * OWs * C4) + (2 * i - 1) * (OWs * C4) + lane;
        const int orow1 = orow0 + OWs * C4;

        // Prime: col j-1 and col j.
        f4 xp0 = z, xp1 = z, xc0 = z, xc1 = z;
        if (j > 0) {
            if (p0) xp0 = x4[xb0 + (j - 1) * C4];
            if (p1) xp1 = x4[xb1 + (j - 1) * C4];
        }
        if (j < Ww) {
            if (p0) xc0 = x4[xb0 + j * C4];
            if (p1) xc1 = x4[xb1 + j * C4];
        }

        for (int t = 0; t < run; ++t, ++j) {
            // Prefetch next column.
            f4 xn0 = z, xn1 = z;
            if (j + 1 < Ww) {
                if (p0) xn0 = x4[xb0 + (j + 1) * C4];
                if (p1) xn1 = x4[xb1 + (j + 1) * C4];
            }

            f4 o00 = bv, o01 = bv, o10 = bv, o11 = bv;
            fma4(o00, xp0, wv[10]); fma4(o00, xc0, wv[8]);
            fma4(o00, xp1, wv[2]);  fma4(o00, xc1, wv[0]);

            fma4(o01, xp0, wv[11]); fma4(o01, xc0, wv[9]);
            fma4(o01, xp1, wv[3]);  fma4(o01, xc1, wv[1]);

            fma4(o10, xp0, wv[14]); fma4(o10, xc0, wv[12]);
            fma4(o10, xp1, wv[6]);  fma4(o10, xc1, wv[4]);

            fma4(o11, xp0, wv[15]); fma4(o11, xc0, wv[13]);
            fma4(o11, xp1, wv[7]);  fma4(o11, xc1, wv[5]);

            const int c0 = (2 * j - 1) * C4;         // ow = 2j-1
            if (p0) {
                if (j > 0)  __builtin_nontemporal_store(o00, &o4[orow0 + c0]);
                if (j < Ww) __builtin_nontemporal_store(o01, &o4[orow0 + c0 + C4]);
            }
            if (p1) {
                if (j > 0)  __builtin_nontemporal_store(o10, &o4[orow1 + c0]);
                if (j < Ww) __builtin_nontemporal_store(o11, &o4[orow1 + c0 + C4]);
            }

            xp0 = xc0; xp1 = xc1; xc0 = xn0; xc1 = xn1;
        }
        g += run;
    }
}

extern "C" void kernel_launch(void* const* d_in, const int* in_sizes, int n_in,
                              void* d_out, int out_size, void* d_ws, size_t ws_size,
                              hipStream_t stream) {
    const float* x = (const float*)d_in[0];
    const float* w = (const float*)d_in[1];
    const float* b = (const float*)d_in[2];
    float* out = (float*)d_out;

    hipLaunchKernelGGL(dwct_kernel, dim3(NBLK), dim3(256), 0, stream, x, w, b, out);
}